// Round 2
// baseline (161.207 us; speedup 1.0000x reference)
//
#include <hip/hip_runtime.h>
#include <math.h>

// Problem constants (fixed shapes from setup_inputs)
#define NB    8
#define CIN   128
#define CO    32
#define CH    64          // 2*CO channels in qk
#define NN    65536       // H*W
#define CHUNKS 128        // column chunks for gram partials
#define COLS_PB (NN/CHUNKS)   // 512 columns per gram block
#define TILE  32          // columns per LDS tile
#define LSTR  72          // LDS row stride (floats), padded

// ---------------------------------------------------------------------------
// Kernel A: per-chunk partial Gram of qk rows:
//   part[b][chunk][qrel*32+krel]  = sum_n q[qrel,n]*k[krel,n]   (q=ch 32..63, k=ch 0..31)
//   partsq[b][chunk][c]           = sum_n qk[c,n]^2
// Deterministic (fixed reduction tree, no atomics).
// ---------------------------------------------------------------------------
__global__ __launch_bounds__(256) void gram_kernel(const float* __restrict__ qk,
                                                   float* __restrict__ part,
                                                   float* __restrict__ partsq) {
    __shared__ float lds[TILE * LSTR];          // [col][channel] transposed tile
    __shared__ float red[4 * 1024 + 4 * 64];    // cross-wave reduction buffer

    const int t = threadIdx.x;
    const int b = blockIdx.y;
    const int chunk = blockIdx.x;

    // loader mapping: thread t loads channel c, column group g (8 cols)
    const int c = t >> 2;
    const int g = t & 3;

    // compute mapping
    const int w = t >> 6;          // wave id 0..3
    const int lane = t & 63;
    const int l16 = lane & 15;
    const int colsub = lane >> 4;  // 0..3
    const int qi0 = 32 + (l16 >> 2) * 8;   // q channel base (32..56)
    const int ki0 = (l16 & 3) * 8;         // k channel base (0..24)

    const float* src = qk + (size_t)b * CH * NN + (size_t)chunk * COLS_PB + (size_t)c * NN;

    float acc[8][8];
#pragma unroll
    for (int i = 0; i < 8; ++i)
#pragma unroll
        for (int j = 0; j < 8; ++j) acc[i][j] = 0.f;
    float sqa[4] = {0.f, 0.f, 0.f, 0.f};

    for (int tile = 0; tile < COLS_PB / TILE; ++tile) {
        // ---- global load: 2 x float4 per thread (coalesced 128B per channel row)
        const float4* s4 = (const float4*)(src + tile * TILE);
        float4 v0 = s4[g * 2];
        float4 v1 = s4[g * 2 + 1];

        __syncthreads();   // previous tile's compute done before overwrite
        // ---- transpose into LDS: lds[col][c]
        float* dst = &lds[(g * 8) * LSTR + c];
        dst[0 * LSTR] = v0.x; dst[1 * LSTR] = v0.y; dst[2 * LSTR] = v0.z; dst[3 * LSTR] = v0.w;
        dst[4 * LSTR] = v1.x; dst[5 * LSTR] = v1.y; dst[6 * LSTR] = v1.z; dst[7 * LSTR] = v1.w;
        __syncthreads();

        // ---- compute: each wave owns 8 cols; 2 passes of 4 cols (one per colsub)
#pragma unroll
        for (int p = 0; p < 2; ++p) {
            const float* row = &lds[(w * 8 + p * 4 + colsub) * LSTR];
            float4 q0 = *(const float4*)(row + qi0);
            float4 q1 = *(const float4*)(row + qi0 + 4);
            float4 k0 = *(const float4*)(row + ki0);
            float4 k1 = *(const float4*)(row + ki0 + 4);
            float qv[8] = {q0.x, q0.y, q0.z, q0.w, q1.x, q1.y, q1.z, q1.w};
            float kv[8] = {k0.x, k0.y, k0.z, k0.w, k1.x, k1.y, k1.z, k1.w};
#pragma unroll
            for (int i = 0; i < 8; ++i)
#pragma unroll
                for (int j = 0; j < 8; ++j)
                    acc[i][j] = fmaf(qv[i], kv[j], acc[i][j]);
            // square-sums: lane handles 4 channels of its column
            float4 sv = *(const float4*)(row + l16 * 4);
            sqa[0] = fmaf(sv.x, sv.x, sqa[0]);
            sqa[1] = fmaf(sv.y, sv.y, sqa[1]);
            sqa[2] = fmaf(sv.z, sv.z, sqa[2]);
            sqa[3] = fmaf(sv.w, sv.w, sqa[3]);
        }
    }

    // ---- reduce across colsub groups within the wave (lanes l, l^16, l^32, l^48)
#pragma unroll
    for (int i = 0; i < 8; ++i)
#pragma unroll
        for (int j = 0; j < 8; ++j) {
            acc[i][j] += __shfl_xor(acc[i][j], 16);
            acc[i][j] += __shfl_xor(acc[i][j], 32);
        }
#pragma unroll
    for (int s = 0; s < 4; ++s) {
        sqa[s] += __shfl_xor(sqa[s], 16);
        sqa[s] += __shfl_xor(sqa[s], 32);
    }

    if (colsub == 0) {   // lanes 0..15 hold wave totals
#pragma unroll
        for (int i = 0; i < 8; ++i)
#pragma unroll
            for (int j = 0; j < 8; ++j)
                red[w * 1024 + l16 * 64 + i * 8 + j] = acc[i][j];
#pragma unroll
        for (int s = 0; s < 4; ++s)
            red[4096 + w * 64 + l16 * 4 + s] = sqa[s];
    }
    __syncthreads();

    // ---- cross-wave reduce + write partials
    for (int idx = t; idx < 1024; idx += 256) {
        float s = red[idx] + red[1024 + idx] + red[2048 + idx] + red[3072 + idx];
        int lw = idx >> 6;
        int i = (idx >> 3) & 7;
        int j = idx & 7;
        int qrel = (lw >> 2) * 8 + i;
        int krel = (lw & 3) * 8 + j;
        part[((size_t)b * CHUNKS + chunk) * 1024 + qrel * 32 + krel] = s;
    }
    if (t < 64) {
        float s = red[4096 + t] + red[4096 + 64 + t] + red[4096 + 128 + t] + red[4096 + 192 + t];
        partsq[((size_t)b * CHUNKS + chunk) * 64 + t] = s;
    }
}

// ---------------------------------------------------------------------------
// Kernel B (merged): per batch: reduce partials over chunks, normalize,
// softmax, W_eff = attn @ w_v, b_eff = attn @ b_v.  8 blocks x 256 threads.
// ---------------------------------------------------------------------------
__global__ __launch_bounds__(256) void finalize_kernel(const float* __restrict__ part,
                                                       const float* __restrict__ partsq,
                                                       const float* __restrict__ w_v,
                                                       const float* __restrict__ b_v,
                                                       const float* __restrict__ temp,
                                                       float* __restrict__ Weff,
                                                       float* __restrict__ beff) {
    __shared__ float sS[1024];
    __shared__ float snorm[64];
    __shared__ float sA[1024];
    const int t = threadIdx.x;
    const int b = blockIdx.x;

    // reduce S over chunks: 1024 values, 4 per thread, unrolled for MLP
    for (int v = t; v < 1024; v += 256) {
        const float* p = part + (size_t)b * CHUNKS * 1024 + v;
        float s = 0.f;
#pragma unroll 16
        for (int ch = 0; ch < CHUNKS; ++ch)
            s += p[(size_t)ch * 1024];
        sS[v] = s;
    }
    // reduce square-sums: 64 values
    if (t < 64) {
        const float* p = partsq + (size_t)b * CHUNKS * 64 + t;
        float s = 0.f;
#pragma unroll 16
        for (int ch = 0; ch < CHUNKS; ++ch)
            s += p[(size_t)ch * 64];
        snorm[t] = fmaxf(sqrtf(s), 1e-12f);
    }
    __syncthreads();

    if (t < 32) {
        const float T = temp[0];
        const float qn = snorm[32 + t];
        float m = -1e30f;
        for (int d = 0; d < 32; ++d)
            m = fmaxf(m, sS[t * 32 + d] / (qn * snorm[d]) * T);
        float sum = 0.f;
        for (int d = 0; d < 32; ++d)
            sum += expf(sS[t * 32 + d] / (qn * snorm[d]) * T - m);
        const float inv = 1.f / sum;
        for (int d = 0; d < 32; ++d)
            sA[t * 32 + d] = expf(sS[t * 32 + d] / (qn * snorm[d]) * T - m) * inv;
    }
    __syncthreads();

    for (int idx = t; idx < CO * CIN; idx += 256) {
        int cc = idx >> 7;
        int ci = idx & 127;
        float s = 0.f;
#pragma unroll
        for (int d = 0; d < 32; ++d) s += sA[cc * 32 + d] * w_v[d * CIN + ci];
        Weff[(size_t)b * CO * CIN + idx] = s;
    }
    if (t < 32) {
        float s = 0.f;
#pragma unroll
        for (int d = 0; d < 32; ++d) s += sA[t * 32 + d] * b_v[d];
        beff[b * CO + t] = s;
    }
}

// ---------------------------------------------------------------------------
// Kernel C: out[b][o][n] = sum_ci Weff[b][o][ci] * x[b][ci][n] + beff[b][o]
// Weff staged in LDS (broadcast ds_read_b128 — no per-lane VMEM for W).
// 4 columns per thread (float4, 16B/lane). acc[32] float4 = 128 VGPRs,
// all indices compile-time (full o-unroll).
// ---------------------------------------------------------------------------
__global__ __launch_bounds__(256) void out_kernel(const float* __restrict__ x,
                                                  const float* __restrict__ Weff,
                                                  const float* __restrict__ beff,
                                                  float* __restrict__ out) {
    __shared__ float4 lw[CO * 32];   // [o][ci4] = 16 KB
    const int b = blockIdx.y;
    const int t = threadIdx.x;

    // stage Weff for this batch into LDS (coalesced float4, conflict-free writes)
    {
        const float4* Wb4 = (const float4*)(Weff + (size_t)b * CO * CIN);
        for (int i = t; i < CO * 32; i += 256) lw[i] = Wb4[i];
    }
    __syncthreads();

    const int n0 = blockIdx.x * 1024 + t * 4;
    const float* xb = x + (size_t)b * CIN * NN + n0;
    const float* bb = beff + b * CO;

    float4 acc[CO];
#pragma unroll
    for (int o = 0; o < CO; ++o) {
        float bv = bb[o];
        acc[o] = make_float4(bv, bv, bv, bv);
    }

    for (int ci4 = 0; ci4 < 32; ++ci4) {
        float4 xv0 = *(const float4*)(xb + (size_t)(ci4 * 4 + 0) * NN);
        float4 xv1 = *(const float4*)(xb + (size_t)(ci4 * 4 + 1) * NN);
        float4 xv2 = *(const float4*)(xb + (size_t)(ci4 * 4 + 2) * NN);
        float4 xv3 = *(const float4*)(xb + (size_t)(ci4 * 4 + 3) * NN);
#pragma unroll
        for (int o = 0; o < CO; ++o) {
            float4 w = lw[o * 32 + ci4];   // broadcast ds_read_b128
            acc[o].x = fmaf(w.x, xv0.x, acc[o].x);
            acc[o].y = fmaf(w.x, xv0.y, acc[o].y);
            acc[o].z = fmaf(w.x, xv0.z, acc[o].z);
            acc[o].w = fmaf(w.x, xv0.w, acc[o].w);
            acc[o].x = fmaf(w.y, xv1.x, acc[o].x);
            acc[o].y = fmaf(w.y, xv1.y, acc[o].y);
            acc[o].z = fmaf(w.y, xv1.z, acc[o].z);
            acc[o].w = fmaf(w.y, xv1.w, acc[o].w);
            acc[o].x = fmaf(w.z, xv2.x, acc[o].x);
            acc[o].y = fmaf(w.z, xv2.y, acc[o].y);
            acc[o].z = fmaf(w.z, xv2.z, acc[o].z);
            acc[o].w = fmaf(w.z, xv2.w, acc[o].w);
            acc[o].x = fmaf(w.w, xv3.x, acc[o].x);
            acc[o].y = fmaf(w.w, xv3.y, acc[o].y);
            acc[o].z = fmaf(w.w, xv3.z, acc[o].z);
            acc[o].w = fmaf(w.w, xv3.w, acc[o].w);
        }
    }

    float* ob = out + (size_t)b * CO * NN + n0;
#pragma unroll
    for (int o = 0; o < CO; ++o)
        *(float4*)(ob + (size_t)o * NN) = acc[o];
}

// ---------------------------------------------------------------------------
extern "C" void kernel_launch(void* const* d_in, const int* in_sizes, int n_in,
                              void* d_out, int out_size, void* d_ws, size_t ws_size,
                              hipStream_t stream) {
    const float* x    = (const float*)d_in[0];
    const float* qk   = (const float*)d_in[1];
    const float* w_v  = (const float*)d_in[2];
    const float* b_v  = (const float*)d_in[3];
    const float* temp = (const float*)d_in[4];
    float* out = (float*)d_out;

    float* part   = (float*)d_ws;                       // NB*CHUNKS*1024 floats (4 MB)
    float* partsq = part + (size_t)NB * CHUNKS * 1024;  // NB*CHUNKS*64 floats (256 KB)
    float* Weff   = partsq + (size_t)NB * CHUNKS * 64;  // NB*CO*CIN floats
    float* beff   = Weff + (size_t)NB * CO * CIN;       // NB*CO floats

    gram_kernel<<<dim3(CHUNKS, NB), 256, 0, stream>>>(qk, part, partsq);
    finalize_kernel<<<dim3(NB), 256, 0, stream>>>(part, partsq, w_v, b_v, temp, Weff, beff);
    out_kernel<<<dim3(NN / 1024, NB), 256, 0, stream>>>(x, Weff, beff, out);
}

// Round 3
// 119.907 us; speedup vs baseline: 1.3444x; 1.3444x over previous
//
#include <hip/hip_runtime.h>
#include <hip/hip_bf16.h>
#include <math.h>

// Problem constants (fixed shapes from setup_inputs)
#define NB    8
#define CIN   128
#define CO    32
#define CH    64          // 2*Co channels in qk
#define NN    65536       // H*W
#define CHUNKS 128        // gram partial chunks per batch (= waves per batch)
#define GXB   32          // gram blocks per batch (4 waves each -> 128 chunks)
#define SPW   (NN/CHUNKS) // 512 spatial columns per wave
#define SLABS (SPW/16)    // 32 K=16 MFMA slabs per wave

typedef __attribute__((ext_vector_type(8))) short bf16x8;
typedef __attribute__((ext_vector_type(16))) float f32x16;

__device__ __forceinline__ short f2bf(float f) {
    union { __hip_bfloat16 h; short s; } u;
    u.h = __float2bfloat16(f);
    return u.s;
}
__device__ __forceinline__ float bf2f(short s) {
    union { __hip_bfloat16 h; short s; } u;
    u.s = s;
    return __bfloat162float(u.h);
}

// ---------------------------------------------------------------------------
// Kernel A (MFMA, no LDS): per-chunk partial Gram via 32x32x16 bf16 MFMA with
// hi/lo split (error ~2^-18).  A = q channels (32..63), B = k channels (0..31),
// both read straight from global in fragment layout (lane&31 = channel row,
// lane>>5 = k-half, 8 consecutive spatial floats per lane).
//   part[b][chunk][qrel*32+krel], partsq[b][chunk][c] as before.
// ---------------------------------------------------------------------------
__global__ __launch_bounds__(256) void gram_kernel(const float* __restrict__ qk,
                                                   float* __restrict__ part,
                                                   float* __restrict__ partsq) {
    const int b = blockIdx.y;
    const int w = threadIdx.x >> 6;
    const int l = threadIdx.x & 63;
    const int chunk = blockIdx.x * 4 + w;
    const int c = l & 31;       // channel (row for A / col for B)
    const int half = l >> 5;    // k-half selector

    const float* qrow = qk + (size_t)b * CH * NN + (size_t)(CO + c) * NN
                        + (size_t)chunk * SPW + half * 8;
    const float* krow = qk + (size_t)b * CH * NN + (size_t)c * NN
                        + (size_t)chunk * SPW + half * 8;

    f32x16 acc = {};
    float sqq = 0.f, sqk = 0.f;

#pragma unroll 4
    for (int s = 0; s < SLABS; ++s) {
        float4 q0 = *(const float4*)(qrow + s * 16);
        float4 q1 = *(const float4*)(qrow + s * 16 + 4);
        float4 k0 = *(const float4*)(krow + s * 16);
        float4 k1 = *(const float4*)(krow + s * 16 + 4);

        float qf[8] = {q0.x, q0.y, q0.z, q0.w, q1.x, q1.y, q1.z, q1.w};
        float kf[8] = {k0.x, k0.y, k0.z, k0.w, k1.x, k1.y, k1.z, k1.w};

        bf16x8 ah, al, bh, bl;
#pragma unroll
        for (int j = 0; j < 8; ++j) {
            short hq = f2bf(qf[j]);
            ah[j] = hq;
            al[j] = f2bf(qf[j] - bf2f(hq));
            short hk = f2bf(kf[j]);
            bh[j] = hk;
            bl[j] = f2bf(kf[j] - bf2f(hk));
            sqq = fmaf(qf[j], qf[j], sqq);   // square-sums in full f32
            sqk = fmaf(kf[j], kf[j], sqk);
        }
        acc = __builtin_amdgcn_mfma_f32_32x32x16_bf16(ah, bh, acc, 0, 0, 0);
        acc = __builtin_amdgcn_mfma_f32_32x32x16_bf16(ah, bl, acc, 0, 0, 0);
        acc = __builtin_amdgcn_mfma_f32_32x32x16_bf16(al, bh, acc, 0, 0, 0);
    }

    // combine the two k-halves' square-sum partials (channel = lane&31 on both)
    sqq += __shfl_xor(sqq, 32);
    sqk += __shfl_xor(sqk, 32);
    if (half == 0) {
        float* psq = partsq + ((size_t)b * CHUNKS + chunk) * 64;
        psq[c] = sqk;          // k channels 0..31
        psq[CO + c] = sqq;     // q channels 32..63
    }

    // C/D layout (m74/m101): col = lane&31, row = (r&3) + 8*(r>>2) + 4*(lane>>5)
    float* pp = part + ((size_t)b * CHUNKS + chunk) * 1024;
#pragma unroll
    for (int r = 0; r < 16; ++r) {
        int row = (r & 3) + 8 * (r >> 2) + 4 * half;   // q index
        pp[row * 32 + c] = acc[r];                     // col = k index
    }
}

// ---------------------------------------------------------------------------
// Kernel B1: reduce partials over chunks -> Sred[b][0..1023]=S, [1024..1087]=sumsq
// (identical to R1)
// ---------------------------------------------------------------------------
__global__ __launch_bounds__(128) void reduce_kernel(const float* __restrict__ part,
                                                     const float* __restrict__ partsq,
                                                     float* __restrict__ Sred) {
    const int b = blockIdx.y;
    const int v = blockIdx.x * 64 + (threadIdx.x >> 1);
    const int h = threadIdx.x & 1;
    float s = 0.f;
    if (v < 1024) {
        const float* p = part + (size_t)b * CHUNKS * 1024 + v;
        for (int ch = h * (CHUNKS / 2); ch < (h + 1) * (CHUNKS / 2); ++ch)
            s += p[(size_t)ch * 1024];
    } else {
        const float* p = partsq + (size_t)b * CHUNKS * 64 + (v - 1024);
        for (int ch = h * (CHUNKS / 2); ch < (h + 1) * (CHUNKS / 2); ++ch)
            s += p[(size_t)ch * 64];
    }
    s += __shfl_xor(s, 1);
    if (h == 0) Sred[b * 1088 + v] = s;
}

// ---------------------------------------------------------------------------
// Kernel B2: per batch: normalize, softmax, W_eff = attn @ w_v, b_eff = attn @ b_v
// (identical to R1)
// ---------------------------------------------------------------------------
__global__ __launch_bounds__(256) void attn_kernel(const float* __restrict__ Sred,
                                                   const float* __restrict__ w_v,
                                                   const float* __restrict__ b_v,
                                                   const float* __restrict__ temp,
                                                   float* __restrict__ Weff,
                                                   float* __restrict__ beff) {
    __shared__ float sS[1024];
    __shared__ float snorm[64];
    __shared__ float sA[1024];
    const int t = threadIdx.x;
    const int b = blockIdx.x;

    for (int i = t; i < 1024; i += 256) sS[i] = Sred[b * 1088 + i];
    if (t < 64) snorm[t] = fmaxf(sqrtf(Sred[b * 1088 + 1024 + t]), 1e-12f);
    __syncthreads();

    if (t < 32) {
        const float T = temp[0];
        const float qn = snorm[32 + t];
        float m = -1e30f;
        for (int d = 0; d < 32; ++d)
            m = fmaxf(m, sS[t * 32 + d] / (qn * snorm[d]) * T);
        float sum = 0.f;
        for (int d = 0; d < 32; ++d)
            sum += expf(sS[t * 32 + d] / (qn * snorm[d]) * T - m);
        const float inv = 1.f / sum;
        for (int d = 0; d < 32; ++d)
            sA[t * 32 + d] = expf(sS[t * 32 + d] / (qn * snorm[d]) * T - m) * inv;
    }
    __syncthreads();

    for (int idx = t; idx < CO * CIN; idx += 256) {
        int cc = idx >> 7;
        int ci = idx & 127;
        float s = 0.f;
#pragma unroll
        for (int d = 0; d < 32; ++d) s += sA[cc * 32 + d] * w_v[d * CIN + ci];
        Weff[(size_t)b * CO * CIN + idx] = s;
    }
    if (t < 32) {
        float s = 0.f;
#pragma unroll
        for (int d = 0; d < 32; ++d) s += sA[t * 32 + d] * b_v[d];
        beff[b * CO + t] = s;
    }
}

// ---------------------------------------------------------------------------
// Kernel C: out[b][o][n] = sum_ci Weff[b][o][ci] * x[b][ci][n] + beff[b][o]
// (identical to R1 v1 — the empirically fastest variant)
// ---------------------------------------------------------------------------
__global__ __launch_bounds__(256) void out_kernel(const float* __restrict__ x,
                                                  const float* __restrict__ Weff,
                                                  const float* __restrict__ beff,
                                                  float* __restrict__ out) {
    const int b = blockIdx.y;
    const int n0 = blockIdx.x * 512 + threadIdx.x * 2;
    const float* xb = x + (size_t)b * CIN * NN + n0;
    const float* Wb = Weff + (size_t)b * CO * CIN;
    const float* bb = beff + b * CO;

    float a0[CO], a1[CO];
#pragma unroll
    for (int o = 0; o < CO; ++o) { a0[o] = bb[o]; a1[o] = bb[o]; }

#pragma unroll 4
    for (int ci = 0; ci < CIN; ++ci) {
        float2 xv = *(const float2*)(xb + (size_t)ci * NN);
#pragma unroll
        for (int o = 0; o < CO; ++o) {
            float wv = Wb[o * CIN + ci];
            a0[o] = fmaf(wv, xv.x, a0[o]);
            a1[o] = fmaf(wv, xv.y, a1[o]);
        }
    }

    float* ob = out + (size_t)b * CO * NN + n0;
#pragma unroll
    for (int o = 0; o < CO; ++o) {
        float2 r;
        r.x = a0[o];
        r.y = a1[o];
        *(float2*)(ob + (size_t)o * NN) = r;
    }
}

// ---------------------------------------------------------------------------
extern "C" void kernel_launch(void* const* d_in, const int* in_sizes, int n_in,
                              void* d_out, int out_size, void* d_ws, size_t ws_size,
                              hipStream_t stream) {
    const float* x    = (const float*)d_in[0];
    const float* qk   = (const float*)d_in[1];
    const float* w_v  = (const float*)d_in[2];
    const float* b_v  = (const float*)d_in[3];
    const float* temp = (const float*)d_in[4];
    float* out = (float*)d_out;

    float* part   = (float*)d_ws;                       // NB*CHUNKS*1024 floats (4 MB)
    float* partsq = part + (size_t)NB * CHUNKS * 1024;  // NB*CHUNKS*64 floats (256 KB)
    float* Sred   = partsq + (size_t)NB * CHUNKS * 64;  // NB*1088 floats
    float* Weff   = Sred + (size_t)NB * 1088;           // NB*CO*CIN floats
    float* beff   = Weff + (size_t)NB * CO * CIN;       // NB*CO floats

    gram_kernel<<<dim3(GXB, NB), 256, 0, stream>>>(qk, part, partsq);
    reduce_kernel<<<dim3(17, NB), 128, 0, stream>>>(part, partsq, Sred);
    attn_kernel<<<dim3(NB), 256, 0, stream>>>(Sred, w_v, b_v, temp, Weff, beff);
    out_kernel<<<dim3(NN / 512, NB), 256, 0, stream>>>(x, Weff, beff, out);
}